// Round 6
// baseline (344.045 us; speedup 1.0000x reference)
//
#include <hip/hip_runtime.h>

#define NN 1024
#define MM 1024
#define DD 256

typedef float floatx2 __attribute__((ext_vector_type(2)));

__device__ __forceinline__ float rcp_fast(float x) { return __builtin_amdgcn_rcpf(x); }

// ---------------- K1: fused dual GEMM + exp epilogue ----------------
// blocks 0..127:   q = f_r @ W_w^T + W_b    -> Qp[n][d] = {A' = exp(-2q), c = w_d*A'}
// blocks 128..255: k = f_rp @ Wp_w^T + Wp_b -> EkT[d][m] = exp(2k)   (LDS-transposed)
// A'-form: w/(e^{2q}e^{2k}+1) = c/(Ek2 + A'), so K2's inner op is add+rcp+fma.
// Block 0 also zeroes d_out for K3's atomicAdd.
__global__ __launch_bounds__(256) void gemm_exp_kernel(
    const float* __restrict__ f_r,  const float* __restrict__ W_w,  const float* __restrict__ W_b,
    const float* __restrict__ f_rp, const float* __restrict__ Wp_w, const float* __restrict__ Wp_b,
    const float* __restrict__ w_w,
    float* __restrict__ Qp, float* __restrict__ EkT, float* __restrict__ out0)
{
    __shared__ float As[32][36];   // [k][r]
    __shared__ float Bs[32][68];   // [k][d]
    __shared__ float T[64][36];    // k-path transpose buffer [d_local][r_local]

    const int b = blockIdx.x;
    const int t = threadIdx.x;
    if (b == 0) out0[t] = 0.f;     // zero d_out (256 floats)

    const int mat  = b >> 7;
    const int tile = b & 127;
    const int rt = tile & 31, dt = tile >> 5;
    const float* __restrict__ A    = mat ? f_rp : f_r;
    const float* __restrict__ B    = mat ? Wp_w : W_w;
    const float* __restrict__ bias = mat ? Wp_b : W_b;

    const int tx = t & 15, ty = t >> 4;          // tx -> 4 d-cols, ty -> 2 r-rows
    const int r0 = rt * 32, d0 = dt * 64;
    const int ar = t >> 3, ak = (t & 7) * 4;     // A stage: 32 rows x 32 k
    const int br = t >> 2, bk = (t & 3) * 8;     // B stage: 64 rows x 32 k

    float acc[2][4];
    #pragma unroll
    for (int i = 0; i < 2; ++i)
        #pragma unroll
        for (int j = 0; j < 4; ++j) acc[i][j] = 0.f;

    for (int kk = 0; kk < DD; kk += 32) {
        float4 av  = *(const float4*)(A + (size_t)(r0 + ar) * DD + kk + ak);
        float4 bv0 = *(const float4*)(B + (size_t)(d0 + br) * DD + kk + bk);
        float4 bv1 = *(const float4*)(B + (size_t)(d0 + br) * DD + kk + bk + 4);
        __syncthreads();
        As[ak + 0][ar] = av.x; As[ak + 1][ar] = av.y; As[ak + 2][ar] = av.z; As[ak + 3][ar] = av.w;
        Bs[bk + 0][br] = bv0.x; Bs[bk + 1][br] = bv0.y; Bs[bk + 2][br] = bv0.z; Bs[bk + 3][br] = bv0.w;
        Bs[bk + 4][br] = bv1.x; Bs[bk + 5][br] = bv1.y; Bs[bk + 6][br] = bv1.z; Bs[bk + 7][br] = bv1.w;
        __syncthreads();
        #pragma unroll
        for (int k = 0; k < 32; ++k) {
            float2 a2 = *(const float2*)&As[k][ty * 2];
            float4 b4 = *(const float4*)&Bs[k][tx * 4];
            float aa[2] = {a2.x, a2.y};
            float bb[4] = {b4.x, b4.y, b4.z, b4.w};
            #pragma unroll
            for (int i = 0; i < 2; ++i)
                #pragma unroll
                for (int j = 0; j < 4; ++j)
                    acc[i][j] = fmaf(aa[i], bb[j], acc[i][j]);
        }
    }

    float bj[4];
    #pragma unroll
    for (int j = 0; j < 4; ++j) bj[j] = bias[d0 + tx * 4 + j];

    if (mat == 0) {
        float wj[4];
        #pragma unroll
        for (int j = 0; j < 4; ++j) wj[j] = w_w[d0 + tx * 4 + j];
        #pragma unroll
        for (int i = 0; i < 2; ++i) {
            float ap[4], cp[4];
            #pragma unroll
            for (int j = 0; j < 4; ++j) {
                float v = acc[i][j] + bj[j];
                // +-5: tanh(5)=0.9999092 (error 9e-5, negligible after w-weighting);
                // also bounds the no-max exp in K2: |s~| <= 2*sum|w| <= 32.
                v = fminf(fmaxf(v, -5.f), 5.f);
                ap[j] = __expf(-2.f * v);        // A' = e^{-2q}
                cp[j] = wj[j] * ap[j];           // c  = w_d * A'
            }
            const size_t ro = (size_t)(r0 + ty * 2 + i) * (2 * DD) + 2 * (d0 + tx * 4);
            *(float4*)&Qp[ro + 0] = make_float4(ap[0], cp[0], ap[1], cp[1]);
            *(float4*)&Qp[ro + 4] = make_float4(ap[2], cp[2], ap[3], cp[3]);
        }
    } else {
        float e[2][4];
        #pragma unroll
        for (int i = 0; i < 2; ++i)
            #pragma unroll
            for (int j = 0; j < 4; ++j) {
                float v = acc[i][j] + bj[j];
                v = fminf(fmaxf(v, -5.f), 5.f);
                e[i][j] = __expf(2.f * v);       // Ek2 = e^{2k}
            }
        __syncthreads();
        #pragma unroll
        for (int i = 0; i < 2; ++i)
            #pragma unroll
            for (int j = 0; j < 4; ++j) T[tx * 4 + j][ty * 2 + i] = e[i][j];
        __syncthreads();
        const int dl = t >> 3, rl = (t & 7) * 4;
        #pragma unroll
        for (int h = 0; h < 2; ++h) {
            int dloc = dl + 32 * h;
            float4 tv = *(const float4*)&T[dloc][rl];
            *(float4*)&EkT[(size_t)(d0 + dloc) * MM + r0 + rl] = tv;
        }
    }
}

// per-m-column accumulate: acc += c / (B + A'), 4 m at once, plain scalar f32.
// 12 VALU (4 add, 4 rcp, 4 fma) per (1 n, 1 d, 4 m) — minimal-instruction form,
// no packed-fp32 dependence, B reused across n straight from the float4 load.
__device__ __forceinline__ void accum4(float4& a, const float4 B, const float2 q) {
    a.x = fmaf(q.y, rcp_fast(B.x + q.x), a.x);
    a.y = fmaf(q.y, rcp_fast(B.y + q.x), a.y);
    a.z = fmaf(q.y, rcp_fast(B.z + q.x), a.z);
    a.w = fmaf(q.y, rcp_fast(B.w + q.x), a.w);
}

// ---------------- K2: m-split mega kernel, A'-form inner loop ----------------
// 512 blocks x 1024 thr; block = (n-quad = bid>>1, m-half = bid&1). 2 blocks/CU.
// Phase A: tg = t>>7 -> d-group of 32; tm = t&127 -> 4 m-cols.
//   acc[n] += c_nd / (Ek2[d][m] + A'_nd): 3 scalar VALU/element, {A',c} via
//   wave-uniform s_loads from Qp (4 consecutive d -> s_load_dwordx8).
// Phase B: 8-slab combine + NO-MAX exp (|s~|<=32 provably); partial denom -> Sp.
// Phase C: ctx~_half = e @ frp[m-half] -> ctxA/B; stage-2 partial score -> sA/sB.
__global__ __launch_bounds__(1024, 8) void fused_attn_kernel(
    const float* __restrict__ Qp, const float* __restrict__ EkT,
    const float* __restrict__ frp, const float* __restrict__ wp_w,
    float* __restrict__ ctxA, float* __restrict__ ctxB,
    float* __restrict__ SpA, float* __restrict__ SpB,
    float* __restrict__ sA,  float* __restrict__ sB)
{
    // union region: accbuf2 (phase A->B) aliases ctxred (phase C); lifetimes
    // separated by the phase-B barrier.
    __shared__ __align__(16) char usm_raw[65536];
    float2 (*accbuf2)[4][256] = (float2 (*)[4][256])(void*)usm_raw;  // [8][4][256] 64KB
    float4 (*ctxred)[4][64]   = (float4 (*)[4][64])(void*)usm_raw;   // [16][4][64] 64KB
    __shared__ float alsm[4][512];   // 8KB unnormalized e
    __shared__ float redsm[4][4];
    __shared__ float redsc[16];

    const int t  = threadIdx.x;
    const int tg = t >> 7;        // d-group (8 x 32 d)
    const int tm = t & 127;       // m-cols m0+4tm .. +3
    const int bm = blockIdx.x & 1;
    const int n0 = (blockIdx.x >> 1) * 4;
    const int m0 = bm * 512;

    // wave-uniform scalar bases (tg constant within a wave: 128 thr = 2 waves/tg)
    const int dbase = __builtin_amdgcn_readfirstlane(tg * 32);
    const float2* __restrict__ qpb = (const float2*)Qp + (size_t)n0 * DD + dbase;
    const float* __restrict__ ekb  = EkT + (size_t)dbase * MM + m0 + 4 * tm;

    // ---- Phase A: scores over 32-d group, 4 m/thread, A'-form ----
    float4 acc[4];
    #pragma unroll
    for (int n = 0; n < 4; ++n) acc[n] = make_float4(0.f, 0.f, 0.f, 0.f);

    #pragma unroll
    for (int dd = 0; dd < 32; dd += 4) {
        float4 B0 = *(const float4*)(ekb + (size_t)(dd + 0) * MM);
        float4 B1 = *(const float4*)(ekb + (size_t)(dd + 1) * MM);
        float4 B2 = *(const float4*)(ekb + (size_t)(dd + 2) * MM);
        float4 B3 = *(const float4*)(ekb + (size_t)(dd + 3) * MM);
        #pragma unroll
        for (int n = 0; n < 4; ++n) {
            const float2* qn = qpb + (size_t)n * DD + dd;   // uniform -> s_load
            float2 q0 = qn[0], q1 = qn[1], q2 = qn[2], q3 = qn[3];
            accum4(acc[n], B0, q0);
            accum4(acc[n], B1, q1);
            accum4(acc[n], B2, q2);
            accum4(acc[n], B3, q3);
        }
    }

    // m-pair j = 2tm holds m(4tm,4tm+1); j = 2tm+1 holds m(4tm+2,4tm+3)
    #pragma unroll
    for (int n = 0; n < 4; ++n)
        *(float4*)&accbuf2[tg][n][2 * tm] = acc[n];
    __syncthreads();

    // ---- Phase B: 8-slab combine + no-max exp; thread -> (n = t>>8, pair j = t&255) ----
    const int bn = t >> 8, j = t & 255;
    const int w4id = (t >> 6) & 3;
    const int lane = t & 63;
    float2 aj = make_float2(0.f, 0.f);
    #pragma unroll
    for (int g8 = 0; g8 < 8; ++g8) {
        float2 v = accbuf2[g8][bn][j];
        aj.x += v.x; aj.y += v.y;
    }
    float ex = __expf(-2.f * aj.x), ey = __expf(-2.f * aj.y);   // bounded: |s~| <= 32
    *(float2*)&alsm[bn][2 * j] = make_float2(ex, ey);
    float sm = ex + ey;
    #pragma unroll
    for (int off = 32; off > 0; off >>= 1) sm += __shfl_xor(sm, off);
    if (lane == 0) redsm[bn][w4id] = sm;
    __syncthreads();   // alsm+redsm ready; accbuf2 dead -> ctxred alias safe
    if (j == 0) {
        float* Sp = bm ? SpB : SpA;
        Sp[n0 + bn] = redsm[bn][0] + redsm[bn][1] + redsm[bn][2] + redsm[bn][3];
    }

    // ---- Phase C: ctx~ = e @ frp over this m-half (m-range split) ----
    const int cc = t & 63;        // d-cols 4cc..4cc+3
    const int rr = t >> 6;        // m-range rr*32 .. +31 (local)
    floatx2 axl[4] = {{0.f,0.f},{0.f,0.f},{0.f,0.f},{0.f,0.f}};
    floatx2 axh[4] = {{0.f,0.f},{0.f,0.f},{0.f,0.f},{0.f,0.f}};
    const float* fb = frp + (size_t)(m0 + rr * 32) * DD + 4 * cc;
    for (int m8 = 0; m8 < 8; ++m8) {
        float alv[4][4];
        #pragma unroll
        for (int n = 0; n < 4; ++n) {
            float4 a4 = *(const float4*)&alsm[n][rr * 32 + m8 * 4];
            alv[n][0] = a4.x; alv[n][1] = a4.y; alv[n][2] = a4.z; alv[n][3] = a4.w;
        }
        #pragma unroll
        for (int mm = 0; mm < 4; ++mm) {
            float4 f = *(const float4*)(fb + (size_t)(m8 * 4 + mm) * DD);
            floatx2 fl = {f.x, f.y}, fh = {f.z, f.w};
            #pragma unroll
            for (int n = 0; n < 4; ++n) {
                axl[n] += alv[n][mm] * fl;
                axh[n] += alv[n][mm] * fh;
            }
        }
    }
    #pragma unroll
    for (int n = 0; n < 4; ++n)
        ctxred[rr][n][cc] = make_float4(axl[n].x, axl[n].y, axh[n].x, axh[n].y);
    __syncthreads();

    // final range-reduce: thread t -> (n = t>>8, d = t&255)
    const int nn = t >> 8, d = t & 255;
    float s = 0.f;
    #pragma unroll
    for (int r = 0; r < 16; ++r)
        s += ((const float*)&ctxred[r][nn][d >> 2])[d & 3];
    float* ctxP = bm ? ctxB : ctxA;
    ctxP[(size_t)(n0 + nn) * DD + d] = s;

    // stage-2 partial score: s~_half[n] = ctx~_half[n] . wp_w
    float p = s * wp_w[d];
    #pragma unroll
    for (int off = 32; off > 0; off >>= 1) p += __shfl_xor(p, off);
    if (lane == 0) redsc[t >> 6] = p;
    __syncthreads();
    if (t < 4) {
        float* sP = bm ? sB : sA;
        sP[n0 + t] = redsc[4 * t] + redsc[4 * t + 1] + redsc[4 * t + 2] + redsc[4 * t + 3];
    }
}

// ---------------- K3: softmax over N (redundant per block) + pooled sum ----------------
// 256 blocks x 256 thr; block b handles n-rows 4b..4b+3.
// score[row] = (sA+sB)/(SpA+SpB) reconstructed from 4 scalars.
__global__ __launch_bounds__(256) void pool_kernel(
    const float* __restrict__ ctxA, const float* __restrict__ ctxB,
    const float* __restrict__ SpA,  const float* __restrict__ SpB,
    const float* __restrict__ sA,   const float* __restrict__ sB,
    float* __restrict__ out)
{
    __shared__ float red[8];
    const int t = threadIdx.x, lane = t & 63, wid = t >> 6;
    const int n0 = blockIdx.x * 4;

    float sc[4];
    #pragma unroll
    for (int i = 0; i < 4; ++i) {
        int r = t + 256 * i;
        sc[i] = (sA[r] + sB[r]) * rcp_fast(SpA[r] + SpB[r]);
    }
    float mx = fmaxf(fmaxf(sc[0], sc[1]), fmaxf(sc[2], sc[3]));
    #pragma unroll
    for (int off = 32; off > 0; off >>= 1) mx = fmaxf(mx, __shfl_xor(mx, off));
    if (lane == 0) red[wid] = mx;
    __syncthreads();
    mx = fmaxf(fmaxf(red[0], red[1]), fmaxf(red[2], red[3]));

    float se = __expf(sc[0] - mx) + __expf(sc[1] - mx) + __expf(sc[2] - mx) + __expf(sc[3] - mx);
    #pragma unroll
    for (int off = 32; off > 0; off >>= 1) se += __shfl_xor(se, off);
    if (lane == 0) red[4 + wid] = se;
    __syncthreads();
    se = red[4] + red[5] + red[6] + red[7];
    float invS = rcp_fast(se);

    float racc = 0.f;
    #pragma unroll
    for (int i = 0; i < 4; ++i) {
        int row = n0 + i;
        float invRow = rcp_fast(SpA[row] + SpB[row]);      // wave-uniform scalar loads
        float scr = (sA[row] + sB[row]) * invRow;
        float ap = __expf(scr - mx) * invS;
        float cr = (ctxA[(size_t)row * DD + t] + ctxB[(size_t)row * DD + t]) * invRow;
        racc = fmaf(ap, cr, racc);
    }
    atomicAdd(out + t, racc);
}

extern "C" void kernel_launch(void* const* d_in, const int* in_sizes, int n_in,
                              void* d_out, int out_size, void* d_ws, size_t ws_size,
                              hipStream_t stream) {
    const float* f_r  = (const float*)d_in[0];
    const float* f_rp = (const float*)d_in[1];
    const float* W_w  = (const float*)d_in[2];
    const float* W_b  = (const float*)d_in[3];
    const float* Wp_w = (const float*)d_in[4];
    const float* Wp_b = (const float*)d_in[5];
    const float* w_w  = (const float*)d_in[6];
    // d_in[7] = w_b  : cancels in softmax over m
    const float* wp_w = (const float*)d_in[8];
    // d_in[9] = wp_b : cancels in softmax over n
    float* out = (float*)d_out;

    float* ws    = (float*)d_ws;
    float* Qp    = ws;                  // 524288 floats (2 MB): {A', c} pairs [N][D]
    float* EkT   = ws + 524288;         // 262144 (1 MB)
    float* ctxA  = ws + 786432;         // 262144 (unnormalized half-0 context)
    float* ctxB  = ws + 1048576;        // 262144 (unnormalized half-1 context)
    float* SpA   = ws + 1310720;        // 1024 (half softmax denominators)
    float* SpB   = ws + 1311744;        // 1024
    float* sA    = ws + 1312768;        // 1024 (half stage-2 partial scores)
    float* sB    = ws + 1313792;        // 1024

    gemm_exp_kernel<<<256, 256, 0, stream>>>(f_r, W_w, W_b, f_rp, Wp_w, Wp_b, w_w,
                                             Qp, EkT, out);
    fused_attn_kernel<<<512, 1024, 0, stream>>>(Qp, EkT, f_rp, wp_w,
                                                ctxA, ctxB, SpA, SpB, sA, sB);
    pool_kernel<<<256, 256, 0, stream>>>(ctxA, ctxB, SpA, SpB, sA, sB, out);
}

// Round 7
// 124.197 us; speedup vs baseline: 2.7702x; 2.7702x over previous
//
#include <hip/hip_runtime.h>

#define NN 1024
#define MM 1024
#define DD 256

typedef float floatx2 __attribute__((ext_vector_type(2)));

__device__ __forceinline__ float rcp_fast(float x) { return __builtin_amdgcn_rcpf(x); }

// ---------------- K1: fused dual GEMM + exp epilogue ----------------
// blocks 0..127:   q = f_r @ W_w^T + W_b    -> Eq[n][d]  = exp(2q)   (clamped +-5)
// blocks 128..255: k = f_rp @ Wp_w^T + Wp_b -> EkT[d][m] = exp(2k)   (LDS-transposed)
// Block 0 also zeroes d_out for K3's atomicAdd.
__global__ __launch_bounds__(256) void gemm_exp_kernel(
    const float* __restrict__ f_r,  const float* __restrict__ W_w,  const float* __restrict__ W_b,
    const float* __restrict__ f_rp, const float* __restrict__ Wp_w, const float* __restrict__ Wp_b,
    float* __restrict__ Eq, float* __restrict__ EkT, float* __restrict__ out0)
{
    __shared__ float As[32][36];   // [k][r]
    __shared__ float Bs[32][68];   // [k][d]
    __shared__ float T[64][36];    // k-path transpose buffer [d_local][r_local]

    const int b = blockIdx.x;
    const int t = threadIdx.x;
    if (b == 0) out0[t] = 0.f;     // zero d_out (256 floats)

    const int mat  = b >> 7;
    const int tile = b & 127;
    const int rt = tile & 31, dt = tile >> 5;
    const float* __restrict__ A    = mat ? f_rp : f_r;
    const float* __restrict__ B    = mat ? Wp_w : W_w;
    const float* __restrict__ bias = mat ? Wp_b : W_b;

    const int tx = t & 15, ty = t >> 4;          // tx -> 4 d-cols, ty -> 2 r-rows
    const int r0 = rt * 32, d0 = dt * 64;
    const int ar = t >> 3, ak = (t & 7) * 4;     // A stage: 32 rows x 32 k
    const int br = t >> 2, bk = (t & 3) * 8;     // B stage: 64 rows x 32 k

    float acc[2][4];
    #pragma unroll
    for (int i = 0; i < 2; ++i)
        #pragma unroll
        for (int j = 0; j < 4; ++j) acc[i][j] = 0.f;

    for (int kk = 0; kk < DD; kk += 32) {
        float4 av  = *(const float4*)(A + (size_t)(r0 + ar) * DD + kk + ak);
        float4 bv0 = *(const float4*)(B + (size_t)(d0 + br) * DD + kk + bk);
        float4 bv1 = *(const float4*)(B + (size_t)(d0 + br) * DD + kk + bk + 4);
        __syncthreads();
        As[ak + 0][ar] = av.x; As[ak + 1][ar] = av.y; As[ak + 2][ar] = av.z; As[ak + 3][ar] = av.w;
        Bs[bk + 0][br] = bv0.x; Bs[bk + 1][br] = bv0.y; Bs[bk + 2][br] = bv0.z; Bs[bk + 3][br] = bv0.w;
        Bs[bk + 4][br] = bv1.x; Bs[bk + 5][br] = bv1.y; Bs[bk + 6][br] = bv1.z; Bs[bk + 7][br] = bv1.w;
        __syncthreads();
        #pragma unroll
        for (int k = 0; k < 32; ++k) {
            float2 a2 = *(const float2*)&As[k][ty * 2];
            float4 b4 = *(const float4*)&Bs[k][tx * 4];
            float aa[2] = {a2.x, a2.y};
            float bb[4] = {b4.x, b4.y, b4.z, b4.w};
            #pragma unroll
            for (int i = 0; i < 2; ++i)
                #pragma unroll
                for (int j = 0; j < 4; ++j)
                    acc[i][j] = fmaf(aa[i], bb[j], acc[i][j]);
        }
    }

    float bj[4];
    #pragma unroll
    for (int j = 0; j < 4; ++j) bj[j] = bias[d0 + tx * 4 + j];

    float e[2][4];
    #pragma unroll
    for (int i = 0; i < 2; ++i)
        #pragma unroll
        for (int j = 0; j < 4; ++j) {
            float v = acc[i][j] + bj[j];
            // +-5: tanh(5)=0.9999092 (error 9e-5, negligible after w-weighting);
            // also bounds the no-max exp in K2: |s~| <= 2*sum|w| <= 32 -> e^32 << fp32 max.
            v = fminf(fmaxf(v, -5.f), 5.f);
            e[i][j] = __expf(2.f * v);
        }

    if (mat == 0) {
        #pragma unroll
        for (int i = 0; i < 2; ++i)
            *(float4*)&Eq[(size_t)(r0 + ty * 2 + i) * DD + d0 + tx * 4] =
                make_float4(e[i][0], e[i][1], e[i][2], e[i][3]);
    } else {
        __syncthreads();
        #pragma unroll
        for (int i = 0; i < 2; ++i)
            #pragma unroll
            for (int j = 0; j < 4; ++j) T[tx * 4 + j][ty * 2 + i] = e[i][j];
        __syncthreads();
        const int dl = t >> 3, rl = (t & 7) * 4;
        #pragma unroll
        for (int h = 0; h < 2; ++h) {
            int dloc = dl + 32 * h;
            float4 tv = *(const float4*)&T[dloc][rl];
            *(float4*)&EkT[(size_t)(d0 + dloc) * MM + r0 + rl] = tv;
        }
    }
}

// ---------------- K2: m-split mega kernel, 4 m/thread ----------------
// 512 blocks x 1024 thr; block = (n-quad = bid>>1, m-half = bid&1).
// ROUND 7: launch_bounds (1024,8)->(1024,4). The (1024,8) variant forces a
// 32-VGPR cap; round-6's spill blowup showed how tight that is. Lifting to
// ~128 VGPRs (1 block/CU resident) lets the compiler pipeline phase A's
// 8-load stream deeper. Round-1 showed 16-vs-32 waves/CU is perf-neutral
// here, so the occupancy cost is established-free.
// Phase A: tg = t>>7 -> d-group of 32; tm = t&127 -> 4 m-cols (float4 EkT loads).
//   s~[n,m] = -2 sum_d w_d/(Eq*Ek+1), 4-way rcp combining, q/w scalar loads.
// Phase B: 8-slab combine + NO-MAX exp (|s~|<=32 provably); partial denom -> Sp.
// Phase C: ctx~_half = e @ frp[m-half] -> ctxA/B; stage-2 partial score -> sA/sB.
__global__ __launch_bounds__(1024, 4) void fused_attn_kernel(
    const float* __restrict__ Eq, const float* __restrict__ EkT,
    const float* __restrict__ w_w, const float* __restrict__ frp,
    const float* __restrict__ wp_w,
    float* __restrict__ ctxA, float* __restrict__ ctxB,
    float* __restrict__ SpA, float* __restrict__ SpB,
    float* __restrict__ sA,  float* __restrict__ sB)
{
    // union region: accbuf2 (phase A->B) aliases ctxred (phase C); lifetimes
    // separated by the phase-B barrier.
    __shared__ __align__(16) char usm_raw[65536];
    float2 (*accbuf2)[4][256] = (float2 (*)[4][256])(void*)usm_raw;  // [8][4][256] 64KB
    float4 (*ctxred)[4][64]   = (float4 (*)[4][64])(void*)usm_raw;   // [16][4][64] 64KB
    __shared__ float alsm[4][512];   // 8KB unnormalized e
    __shared__ float redsm[4][4];
    __shared__ float redsc[16];

    const int t  = threadIdx.x;
    const int tg = t >> 7;        // d-group (8 x 32 d)
    const int tm = t & 127;       // m-cols m0+4tm .. +3
    const int bm = blockIdx.x & 1;
    const int n0 = (blockIdx.x >> 1) * 4;
    const int m0 = bm * 512;

    // wave-uniform scalar bases (tg constant within a wave: 128 thr = 2 waves/tg)
    const int dh = __builtin_amdgcn_readfirstlane(tg * 32);
    const float* __restrict__ eqb = Eq + (size_t)n0 * DD + dh;
    const float* __restrict__ wwb = w_w + dh;

    // ---- Phase A: scores over 32-d group, 4 m/thread ----
    const floatx2 one2 = {1.f, 1.f};
    floatx2 accl[4] = {{0.f,0.f},{0.f,0.f},{0.f,0.f},{0.f,0.f}};   // m 4tm..+1 per n
    floatx2 acch[4] = {{0.f,0.f},{0.f,0.f},{0.f,0.f},{0.f,0.f}};   // m 4tm+2..+3 per n

    const float* ekb = EkT + (size_t)dh * MM + m0 + 4 * tm;

    for (int gi = 0; gi < 8; ++gi) {
        const float* nb = ekb + (size_t)(gi * 4) * MM;
        float4 c0 = *(const float4*)(nb + 0 * MM);
        float4 c1 = *(const float4*)(nb + 1 * MM);
        float4 c2 = *(const float4*)(nb + 2 * MM);
        float4 c3 = *(const float4*)(nb + 3 * MM);
        const int db = gi * 4;
        float4 w4 = *(const float4*)(wwb + db);            // scalar (uniform)
        floatx2 kv[4][2] = {{{c0.x, c0.y}, {c0.z, c0.w}},
                            {{c1.x, c1.y}, {c1.z, c1.w}},
                            {{c2.x, c2.y}, {c2.z, c2.w}},
                            {{c3.x, c3.y}, {c3.z, c3.w}}};
        #pragma unroll
        for (int n = 0; n < 4; ++n) {
            float4 q4 = *(const float4*)(eqb + n * DD + db);   // scalar (uniform)
            #pragma unroll
            for (int h = 0; h < 2; ++h) {
                floatx2 x0 = q4.x * kv[0][h] + one2;
                floatx2 x1 = q4.y * kv[1][h] + one2;
                floatx2 x2 = q4.z * kv[2][h] + one2;
                floatx2 x3 = q4.w * kv[3][h] + one2;
                floatx2 p01 = x0 * x1;
                floatx2 p23 = x2 * x3;
                floatx2 n01 = w4.x * x1 + w4.y * x0;
                floatx2 n23 = w4.z * x3 + w4.w * x2;
                floatx2 nc  = n01 * p23 + n23 * p01;
                floatx2 pt  = p01 * p23;
                floatx2 r;  r.x = rcp_fast(pt.x);  r.y = rcp_fast(pt.y);
                if (h == 0) accl[n] += nc * r; else acch[n] += nc * r;
            }
        }
    }

    // m-pair j = 2tm holds m(4tm,4tm+1); j = 2tm+1 holds m(4tm+2,4tm+3)
    #pragma unroll
    for (int n = 0; n < 4; ++n)
        *(float4*)&accbuf2[tg][n][2 * tm] =
            make_float4(accl[n].x, accl[n].y, acch[n].x, acch[n].y);
    __syncthreads();

    // ---- Phase B: 8-slab combine + no-max exp; thread -> (n = t>>8, pair j = t&255) ----
    const int bn = t >> 8, j = t & 255;
    const int w4id = (t >> 6) & 3;
    const int lane = t & 63;
    float2 aj = make_float2(0.f, 0.f);
    #pragma unroll
    for (int g8 = 0; g8 < 8; ++g8) {
        float2 v = accbuf2[g8][bn][j];
        aj.x += v.x; aj.y += v.y;
    }
    float ex = __expf(-2.f * aj.x), ey = __expf(-2.f * aj.y);   // bounded: |s~| <= 32
    *(float2*)&alsm[bn][2 * j] = make_float2(ex, ey);
    float sm = ex + ey;
    #pragma unroll
    for (int off = 32; off > 0; off >>= 1) sm += __shfl_xor(sm, off);
    if (lane == 0) redsm[bn][w4id] = sm;
    __syncthreads();   // alsm+redsm ready; accbuf2 dead -> ctxred alias safe
    if (j == 0) {
        float* Sp = bm ? SpB : SpA;
        Sp[n0 + bn] = redsm[bn][0] + redsm[bn][1] + redsm[bn][2] + redsm[bn][3];
    }

    // ---- Phase C: ctx~ = e @ frp over this m-half (m-range split) ----
    const int cc = t & 63;        // d-cols 4cc..4cc+3
    const int rr = t >> 6;        // m-range rr*32 .. +31 (local)
    floatx2 axl[4] = {{0.f,0.f},{0.f,0.f},{0.f,0.f},{0.f,0.f}};
    floatx2 axh[4] = {{0.f,0.f},{0.f,0.f},{0.f,0.f},{0.f,0.f}};
    const float* fb = frp + (size_t)(m0 + rr * 32) * DD + 4 * cc;
    for (int m8 = 0; m8 < 8; ++m8) {
        float alv[4][4];
        #pragma unroll
        for (int n = 0; n < 4; ++n) {
            float4 a4 = *(const float4*)&alsm[n][rr * 32 + m8 * 4];
            alv[n][0] = a4.x; alv[n][1] = a4.y; alv[n][2] = a4.z; alv[n][3] = a4.w;
        }
        #pragma unroll
        for (int mm = 0; mm < 4; ++mm) {
            float4 f = *(const float4*)(fb + (size_t)(m8 * 4 + mm) * DD);
            floatx2 fl = {f.x, f.y}, fh = {f.z, f.w};
            #pragma unroll
            for (int n = 0; n < 4; ++n) {
                axl[n] += alv[n][mm] * fl;
                axh[n] += alv[n][mm] * fh;
            }
        }
    }
    #pragma unroll
    for (int n = 0; n < 4; ++n)
        ctxred[rr][n][cc] = make_float4(axl[n].x, axl[n].y, axh[n].x, axh[n].y);
    __syncthreads();

    // final range-reduce: thread t -> (n = t>>8, d = t&255)
    const int nn = t >> 8, d = t & 255;
    float s = 0.f;
    #pragma unroll
    for (int r = 0; r < 16; ++r)
        s += ((const float*)&ctxred[r][nn][d >> 2])[d & 3];
    float* ctxP = bm ? ctxB : ctxA;
    ctxP[(size_t)(n0 + nn) * DD + d] = s;

    // stage-2 partial score: s~_half[n] = ctx~_half[n] . wp_w
    float p = s * wp_w[d];
    #pragma unroll
    for (int off = 32; off > 0; off >>= 1) p += __shfl_xor(p, off);
    if (lane == 0) redsc[t >> 6] = p;
    __syncthreads();
    if (t < 4) {
        float* sP = bm ? sB : sA;
        sP[n0 + t] = redsc[4 * t] + redsc[4 * t + 1] + redsc[4 * t + 2] + redsc[4 * t + 3];
    }
}

// ---------------- K3: softmax over N (redundant per block) + pooled sum ----------------
// 256 blocks x 256 thr; block b handles n-rows 4b..4b+3.
// score[row] = (sA+sB)/(SpA+SpB) reconstructed from 4 scalars.
__global__ __launch_bounds__(256) void pool_kernel(
    const float* __restrict__ ctxA, const float* __restrict__ ctxB,
    const float* __restrict__ SpA,  const float* __restrict__ SpB,
    const float* __restrict__ sA,   const float* __restrict__ sB,
    float* __restrict__ out)
{
    __shared__ float red[8];
    const int t = threadIdx.x, lane = t & 63, wid = t >> 6;
    const int n0 = blockIdx.x * 4;

    float sc[4];
    #pragma unroll
    for (int i = 0; i < 4; ++i) {
        int r = t + 256 * i;
        sc[i] = (sA[r] + sB[r]) * rcp_fast(SpA[r] + SpB[r]);
    }
    float mx = fmaxf(fmaxf(sc[0], sc[1]), fmaxf(sc[2], sc[3]));
    #pragma unroll
    for (int off = 32; off > 0; off >>= 1) mx = fmaxf(mx, __shfl_xor(mx, off));
    if (lane == 0) red[wid] = mx;
    __syncthreads();
    mx = fmaxf(fmaxf(red[0], red[1]), fmaxf(red[2], red[3]));

    float se = __expf(sc[0] - mx) + __expf(sc[1] - mx) + __expf(sc[2] - mx) + __expf(sc[3] - mx);
    #pragma unroll
    for (int off = 32; off > 0; off >>= 1) se += __shfl_xor(se, off);
    if (lane == 0) red[4 + wid] = se;
    __syncthreads();
    se = red[4] + red[5] + red[6] + red[7];
    float invS = rcp_fast(se);

    float racc = 0.f;
    #pragma unroll
    for (int i = 0; i < 4; ++i) {
        int row = n0 + i;
        float invRow = rcp_fast(SpA[row] + SpB[row]);      // wave-uniform scalar loads
        float scr = (sA[row] + sB[row]) * invRow;
        float ap = __expf(scr - mx) * invS;
        float cr = (ctxA[(size_t)row * DD + t] + ctxB[(size_t)row * DD + t]) * invRow;
        racc = fmaf(ap, cr, racc);
    }
    atomicAdd(out + t, racc);
}

extern "C" void kernel_launch(void* const* d_in, const int* in_sizes, int n_in,
                              void* d_out, int out_size, void* d_ws, size_t ws_size,
                              hipStream_t stream) {
    const float* f_r  = (const float*)d_in[0];
    const float* f_rp = (const float*)d_in[1];
    const float* W_w  = (const float*)d_in[2];
    const float* W_b  = (const float*)d_in[3];
    const float* Wp_w = (const float*)d_in[4];
    const float* Wp_b = (const float*)d_in[5];
    const float* w_w  = (const float*)d_in[6];
    // d_in[7] = w_b  : cancels in softmax over m
    const float* wp_w = (const float*)d_in[8];
    // d_in[9] = wp_b : cancels in softmax over n
    float* out = (float*)d_out;

    float* ws    = (float*)d_ws;
    float* Eq    = ws;                  // 256K floats
    float* EkT   = ws + 262144;         // 256K
    float* ctxA  = ws + 524288;         // 256K (unnormalized half-0 context)
    float* ctxB  = ws + 786432;         // 256K (unnormalized half-1 context)
    float* SpA   = ws + 1048576;        // 1K (half softmax denominators)
    float* SpB   = ws + 1049600;        // 1K
    float* sA    = ws + 1050624;        // 1K (half stage-2 partial scores)
    float* sB    = ws + 1051648;        // 1K

    gemm_exp_kernel<<<256, 256, 0, stream>>>(f_r, W_w, W_b, f_rp, Wp_w, Wp_b, Eq, EkT, out);
    fused_attn_kernel<<<512, 1024, 0, stream>>>(Eq, EkT, w_w, f_rp, wp_w,
                                                ctxA, ctxB, SpA, SpB, sA, sB);
    pool_kernel<<<256, 256, 0, stream>>>(ctxA, ctxB, SpA, SpB, sA, sB, out);
}

// Round 8
// 121.850 us; speedup vs baseline: 2.8235x; 1.0193x over previous
//
#include <hip/hip_runtime.h>

#define NN 1024
#define MM 1024
#define DD 256

typedef float floatx2 __attribute__((ext_vector_type(2)));

__device__ __forceinline__ float rcp_fast(float x) { return __builtin_amdgcn_rcpf(x); }

// ---- hand-emitted packed-fp32 VOP3P (LLVM won't auto-form these from ext-vector f32) ----
__device__ __forceinline__ floatx2 pk_mul(floatx2 a, floatx2 b) {
    floatx2 d;
    asm("v_pk_mul_f32 %0, %1, %2" : "=v"(d) : "v"(a), "v"(b));
    return d;
}
__device__ __forceinline__ floatx2 pk_fma(floatx2 a, floatx2 b, floatx2 c) {
    floatx2 d;
    asm("v_pk_fma_f32 %0, %1, %2, %3" : "=v"(d) : "v"(a), "v"(b), "v"(c));
    return d;
}
// uniform-operand variants: b lives in an even-aligned SGPR pair (1 SGPR read/instr — legal)
__device__ __forceinline__ floatx2 pk_mul_vs(floatx2 a, floatx2 b) {
    floatx2 d;
    asm("v_pk_mul_f32 %0, %1, %2" : "=v"(d) : "v"(a), "s"(b));
    return d;
}
__device__ __forceinline__ floatx2 pk_fma_vs(floatx2 a, floatx2 b, floatx2 c) {
    floatx2 d;
    asm("v_pk_fma_f32 %0, %1, %2, %3" : "=v"(d) : "v"(a), "s"(b), "v"(c));
    return d;
}

// ---------------- K1: fused dual GEMM + exp epilogue ----------------
// blocks 0..127:   q = f_r @ W_w^T + W_b    -> Eq[n][d] = exp(2q)  (clamped +-5)
// blocks 128..255: k = f_rp @ Wp_w^T + Wp_b -> Ek4 in d-quad-interleaved layout:
//   element (m, d) at Ek4[(d>>2)*4*MM + m*4 + (d&3)] — so K2's per-m float4 load
//   of 4 consecutive d is coalesced across consecutive-m lanes.
// Block 0 also zeroes d_out for K3's atomicAdd.
__global__ __launch_bounds__(256) void gemm_exp_kernel(
    const float* __restrict__ f_r,  const float* __restrict__ W_w,  const float* __restrict__ W_b,
    const float* __restrict__ f_rp, const float* __restrict__ Wp_w, const float* __restrict__ Wp_b,
    float* __restrict__ Eq, float* __restrict__ Ek4, float* __restrict__ out0)
{
    __shared__ float As[32][36];   // [k][r]
    __shared__ float Bs[32][68];   // [k][d]
    __shared__ float4 T4[32][17];  // k-path exchange: [m_local][dq_local], +1 pad

    const int b = blockIdx.x;
    const int t = threadIdx.x;
    if (b == 0) out0[t] = 0.f;     // zero d_out (256 floats)

    const int mat  = b >> 7;
    const int tile = b & 127;
    const int rt = tile & 31, dt = tile >> 5;
    const float* __restrict__ A    = mat ? f_rp : f_r;
    const float* __restrict__ B    = mat ? Wp_w : W_w;
    const float* __restrict__ bias = mat ? Wp_b : W_b;

    const int tx = t & 15, ty = t >> 4;          // tx -> 4 d-cols (one d-quad), ty -> 2 r-rows
    const int r0 = rt * 32, d0 = dt * 64;
    const int ar = t >> 3, ak = (t & 7) * 4;     // A stage: 32 rows x 32 k
    const int br = t >> 2, bk = (t & 3) * 8;     // B stage: 64 rows x 32 k

    float acc[2][4];
    #pragma unroll
    for (int i = 0; i < 2; ++i)
        #pragma unroll
        for (int j = 0; j < 4; ++j) acc[i][j] = 0.f;

    for (int kk = 0; kk < DD; kk += 32) {
        float4 av  = *(const float4*)(A + (size_t)(r0 + ar) * DD + kk + ak);
        float4 bv0 = *(const float4*)(B + (size_t)(d0 + br) * DD + kk + bk);
        float4 bv1 = *(const float4*)(B + (size_t)(d0 + br) * DD + kk + bk + 4);
        __syncthreads();
        As[ak + 0][ar] = av.x; As[ak + 1][ar] = av.y; As[ak + 2][ar] = av.z; As[ak + 3][ar] = av.w;
        Bs[bk + 0][br] = bv0.x; Bs[bk + 1][br] = bv0.y; Bs[bk + 2][br] = bv0.z; Bs[bk + 3][br] = bv0.w;
        Bs[bk + 4][br] = bv1.x; Bs[bk + 5][br] = bv1.y; Bs[bk + 6][br] = bv1.z; Bs[bk + 7][br] = bv1.w;
        __syncthreads();
        #pragma unroll
        for (int k = 0; k < 32; ++k) {
            float2 a2 = *(const float2*)&As[k][ty * 2];
            float4 b4 = *(const float4*)&Bs[k][tx * 4];
            float aa[2] = {a2.x, a2.y};
            float bb[4] = {b4.x, b4.y, b4.z, b4.w};
            #pragma unroll
            for (int i = 0; i < 2; ++i)
                #pragma unroll
                for (int j = 0; j < 4; ++j)
                    acc[i][j] = fmaf(aa[i], bb[j], acc[i][j]);
        }
    }

    float bj[4];
    #pragma unroll
    for (int j = 0; j < 4; ++j) bj[j] = bias[d0 + tx * 4 + j];

    float e[2][4];
    #pragma unroll
    for (int i = 0; i < 2; ++i)
        #pragma unroll
        for (int j = 0; j < 4; ++j) {
            float v = acc[i][j] + bj[j];
            // +-5: tanh(5)=0.9999092 (error 9e-5, negligible after w-weighting);
            // also bounds the no-max exp in K2: |s~| <= 2*sum|w| <= 32 -> e^32 << fp32 max.
            v = fminf(fmaxf(v, -5.f), 5.f);
            e[i][j] = __expf(2.f * v);
        }

    if (mat == 0) {
        #pragma unroll
        for (int i = 0; i < 2; ++i)
            *(float4*)&Eq[(size_t)(r0 + ty * 2 + i) * DD + d0 + tx * 4] =
                make_float4(e[i][0], e[i][1], e[i][2], e[i][3]);
    } else {
        // thread holds m = r0+ty*2+i, d-quad dq_local = tx, j = d&3 contiguous.
        __syncthreads();
        #pragma unroll
        for (int i = 0; i < 2; ++i)
            T4[ty * 2 + i][tx] = make_float4(e[i][0], e[i][1], e[i][2], e[i][3]);
        __syncthreads();
        const int sm = t & 31, sq = t >> 5;   // sm -> m_local, sq -> dq_local (2 halves)
        #pragma unroll
        for (int h = 0; h < 2; ++h) {
            const int dql = sq + 8 * h;
            float4 v = T4[sm][dql];
            // coalesced: consecutive sm lanes -> consecutive m -> +16B stride
            *(float4*)&Ek4[(size_t)((d0 >> 2) + dql) * (4 * MM) + (size_t)(r0 + sm) * 4] = v;
        }
    }
}

// ---------------- K2: m-split mega kernel, d-packed VOP3P phase A ----------------
// 512 blocks x 1024 thr; block = (n-quad = bid>>1, m-half = bid&1).
// Phase A (REWRITTEN): lane owns ONE m (m_l = t&511), tg = t>>9 -> d-half of 128.
//   Ek4 float4 load = 4 consecutive d at this m (coalesced across lanes);
//   Eq/w pairs of consecutive d come from s_load as aligned SGPR pairs -> both
//   pk operands carry real data (no broadcast). 2-level num/den combine:
//   14 v_pk + 2 v_rcp per (n, 8d) vs ~28 scalar + 2 rcp before (1.64x VALU cut).
//   4-way products bounded by e^80 < fp32 max (same depth as the passing r2 code).
// Phase B: 2-slab combine + NO-MAX exp (|s~|<=32); partial denom -> Sp.   [round-2 shape]
// Phase C: ctx~_half = e @ frp[m-half] -> ctxA/B; stage-2 partial score -> sA/sB. [unchanged]
__global__ __launch_bounds__(1024, 4) void fused_attn_kernel(
    const float* __restrict__ Eq, const float* __restrict__ Ek4,
    const float* __restrict__ w_w, const float* __restrict__ frp,
    const float* __restrict__ wp_w,
    float* __restrict__ ctxA, float* __restrict__ ctxB,
    float* __restrict__ SpA, float* __restrict__ SpB,
    float* __restrict__ sA,  float* __restrict__ sB)
{
    // union region: part (phase A->B, 16KB) aliases ctxred (phase C, 64KB);
    // lifetimes separated by the phase-B barrier.
    __shared__ __align__(16) char usm_raw[65536];
    float (*part)[4][512]   = (float (*)[4][512])(void*)usm_raw;   // [2][4][512] 16KB
    float4 (*ctxred)[4][64] = (float4 (*)[4][64])(void*)usm_raw;   // [16][4][64] 64KB
    __shared__ float alsm[4][512];   // 8KB unnormalized e
    __shared__ float redsm[4][4];
    __shared__ float redsc[16];

    const int t   = threadIdx.x;
    const int m_l = t & 511;      // lane's m within the half
    const int tg  = t >> 9;       // d-half (wave-uniform)
    const int bm  = blockIdx.x & 1;
    const int n0  = (blockIdx.x >> 1) * 4;
    const int m0  = bm * 512;

    // wave-uniform scalar bases
    const int dbase = __builtin_amdgcn_readfirstlane(tg * 128);
    const float* __restrict__ eqb = Eq + (size_t)n0 * DD + dbase;
    const float* __restrict__ wwb = w_w + dbase;
    const float* __restrict__ ekb = Ek4 + (size_t)(dbase >> 2) * (4 * MM) + (size_t)(m0 + m_l) * 4;

    // ---- Phase A: 128 d per thread in 16 chunks of 8, all-pk inner loop ----
    const floatx2 one2 = {1.f, 1.f};
    floatx2 acc[4] = {{0.f,0.f},{0.f,0.f},{0.f,0.f},{0.f,0.f}};

    for (int c8 = 0; c8 < 16; ++c8) {
        float4 ekA = *(const float4*)(ekb + (size_t)(2 * c8 + 0) * (4 * MM));
        float4 ekB = *(const float4*)(ekb + (size_t)(2 * c8 + 1) * (4 * MM));
        floatx2 ek01 = {ekA.x, ekA.y}, ek23 = {ekA.z, ekA.w};
        floatx2 ek45 = {ekB.x, ekB.y}, ek67 = {ekB.z, ekB.w};
        const int db = c8 * 8;
        floatx2 w01 = *(const floatx2*)(wwb + db + 0);   // uniform -> SGPR pairs
        floatx2 w23 = *(const floatx2*)(wwb + db + 2);
        floatx2 w45 = *(const floatx2*)(wwb + db + 4);
        floatx2 w67 = *(const floatx2*)(wwb + db + 6);
        #pragma unroll
        for (int n = 0; n < 4; ++n) {
            const float* qn = eqb + (size_t)n * DD + db;   // uniform -> s_load
            floatx2 q01 = *(const floatx2*)(qn + 0);
            floatx2 q23 = *(const floatx2*)(qn + 2);
            floatx2 q45 = *(const floatx2*)(qn + 4);
            floatx2 q67 = *(const floatx2*)(qn + 6);
            // x_d = Eq*Ek + 1 (per-half independent d's)
            floatx2 x01 = pk_fma_vs(ek01, q01, one2);
            floatx2 x23 = pk_fma_vs(ek23, q23, one2);
            floatx2 x45 = pk_fma_vs(ek45, q45, one2);
            floatx2 x67 = pk_fma_vs(ek67, q67, one2);
            // level 1: w/x pairwise combine
            floatx2 den1 = pk_mul(x01, x23);
            floatx2 num1 = pk_fma_vs(x01, w23, pk_mul_vs(x23, w01));
            floatx2 den2 = pk_mul(x45, x67);
            floatx2 num2 = pk_fma_vs(x45, w67, pk_mul_vs(x67, w45));
            // level 2: 4-way products (<= e^80, fp32-safe)
            floatx2 DEN = pk_mul(den1, den2);
            floatx2 NUM = pk_fma(num2, den1, pk_mul(num1, den2));
            floatx2 r2; r2.x = rcp_fast(DEN.x); r2.y = rcp_fast(DEN.y);
            acc[n] = pk_fma(NUM, r2, acc[n]);
        }
    }

    #pragma unroll
    for (int n = 0; n < 4; ++n)
        part[tg][n][m_l] = acc[n].x + acc[n].y;   // conflict-free: stride-1 lanes
    __syncthreads();

    // ---- Phase B: 2-slab combine + no-max exp; thread -> (n = t>>8, m-pair j = t&255) ----
    const int bn = t >> 8, j = t & 255;
    const int w4id = (t >> 6) & 3;
    const int lane = t & 63;
    float2 a0 = *(const float2*)&part[0][bn][2 * j];
    float2 a1 = *(const float2*)&part[1][bn][2 * j];
    float sx = a0.x + a1.x, sy = a0.y + a1.y;
    float ex = __expf(-2.f * sx), ey = __expf(-2.f * sy);   // bounded: |s~| <= 32
    *(float2*)&alsm[bn][2 * j] = make_float2(ex, ey);
    float sm = ex + ey;
    #pragma unroll
    for (int off = 32; off > 0; off >>= 1) sm += __shfl_xor(sm, off);
    if (lane == 0) redsm[bn][w4id] = sm;
    __syncthreads();   // alsm+redsm ready; part dead -> ctxred alias safe
    if (j == 0) {
        float* Sp = bm ? SpB : SpA;
        Sp[n0 + bn] = redsm[bn][0] + redsm[bn][1] + redsm[bn][2] + redsm[bn][3];
    }

    // ---- Phase C: ctx~ = e @ frp over this m-half (m-range split) ----
    const int cc = t & 63;        // d-cols 4cc..4cc+3
    const int rr = t >> 6;        // m-range rr*32 .. +31 (local)
    floatx2 axl[4] = {{0.f,0.f},{0.f,0.f},{0.f,0.f},{0.f,0.f}};
    floatx2 axh[4] = {{0.f,0.f},{0.f,0.f},{0.f,0.f},{0.f,0.f}};
    const float* fb = frp + (size_t)(m0 + rr * 32) * DD + 4 * cc;
    for (int m8 = 0; m8 < 8; ++m8) {
        float alv[4][4];
        #pragma unroll
        for (int n = 0; n < 4; ++n) {
            float4 a4 = *(const float4*)&alsm[n][rr * 32 + m8 * 4];
            alv[n][0] = a4.x; alv[n][1] = a4.y; alv[n][2] = a4.z; alv[n][3] = a4.w;
        }
        #pragma unroll
        for (int mm = 0; mm < 4; ++mm) {
            float4 f = *(const float4*)(fb + (size_t)(m8 * 4 + mm) * DD);
            floatx2 fl = {f.x, f.y}, fh = {f.z, f.w};
            #pragma unroll
            for (int n = 0; n < 4; ++n) {
                axl[n] += alv[n][mm] * fl;
                axh[n] += alv[n][mm] * fh;
            }
        }
    }
    #pragma unroll
    for (int n = 0; n < 4; ++n)
        ctxred[rr][n][cc] = make_float4(axl[n].x, axl[n].y, axh[n].x, axh[n].y);
    __syncthreads();

    // final range-reduce: thread t -> (n = t>>8, d = t&255)
    const int nn = t >> 8, d = t & 255;
    float s = 0.f;
    #pragma unroll
    for (int r = 0; r < 16; ++r)
        s += ((const float*)&ctxred[r][nn][d >> 2])[d & 3];
    float* ctxP = bm ? ctxB : ctxA;
    ctxP[(size_t)(n0 + nn) * DD + d] = s;

    // stage-2 partial score: s~_half[n] = ctx~_half[n] . wp_w
    float p = s * wp_w[d];
    #pragma unroll
    for (int off = 32; off > 0; off >>= 1) p += __shfl_xor(p, off);
    if (lane == 0) redsc[t >> 6] = p;
    __syncthreads();
    if (t < 4) {
        float* sP = bm ? sB : sA;
        sP[n0 + t] = redsc[4 * t] + redsc[4 * t + 1] + redsc[4 * t + 2] + redsc[4 * t + 3];
    }
}

// ---------------- K3: softmax over N (redundant per block) + pooled sum ----------------
// 256 blocks x 256 thr; block b handles n-rows 4b..4b+3.
// score[row] = (sA+sB)/(SpA+SpB) reconstructed from 4 scalars.
__global__ __launch_bounds__(256) void pool_kernel(
    const float* __restrict__ ctxA, const float* __restrict__ ctxB,
    const float* __restrict__ SpA,  const float* __restrict__ SpB,
    const float* __restrict__ sA,   const float* __restrict__ sB,
    float* __restrict__ out)
{
    __shared__ float red[8];
    const int t = threadIdx.x, lane = t & 63, wid = t >> 6;
    const int n0 = blockIdx.x * 4;

    float sc[4];
    #pragma unroll
    for (int i = 0; i < 4; ++i) {
        int r = t + 256 * i;
        sc[i] = (sA[r] + sB[r]) * rcp_fast(SpA[r] + SpB[r]);
    }
    float mx = fmaxf(fmaxf(sc[0], sc[1]), fmaxf(sc[2], sc[3]));
    #pragma unroll
    for (int off = 32; off > 0; off >>= 1) mx = fmaxf(mx, __shfl_xor(mx, off));
    if (lane == 0) red[wid] = mx;
    __syncthreads();
    mx = fmaxf(fmaxf(red[0], red[1]), fmaxf(red[2], red[3]));

    float se = __expf(sc[0] - mx) + __expf(sc[1] - mx) + __expf(sc[2] - mx) + __expf(sc[3] - mx);
    #pragma unroll
    for (int off = 32; off > 0; off >>= 1) se += __shfl_xor(se, off);
    if (lane == 0) red[4 + wid] = se;
    __syncthreads();
    se = red[4] + red[5] + red[6] + red[7];
    float invS = rcp_fast(se);

    float racc = 0.f;
    #pragma unroll
    for (int i = 0; i < 4; ++i) {
        int row = n0 + i;
        float invRow = rcp_fast(SpA[row] + SpB[row]);      // wave-uniform scalar loads
        float scr = (sA[row] + sB[row]) * invRow;
        float ap = __expf(scr - mx) * invS;
        float cr = (ctxA[(size_t)row * DD + t] + ctxB[(size_t)row * DD + t]) * invRow;
        racc = fmaf(ap, cr, racc);
    }
    atomicAdd(out + t, racc);
}

extern "C" void kernel_launch(void* const* d_in, const int* in_sizes, int n_in,
                              void* d_out, int out_size, void* d_ws, size_t ws_size,
                              hipStream_t stream) {
    const float* f_r  = (const float*)d_in[0];
    const float* f_rp = (const float*)d_in[1];
    const float* W_w  = (const float*)d_in[2];
    const float* W_b  = (const float*)d_in[3];
    const float* Wp_w = (const float*)d_in[4];
    const float* Wp_b = (const float*)d_in[5];
    const float* w_w  = (const float*)d_in[6];
    // d_in[7] = w_b  : cancels in softmax over m
    const float* wp_w = (const float*)d_in[8];
    // d_in[9] = wp_b : cancels in softmax over n
    float* out = (float*)d_out;

    float* ws    = (float*)d_ws;
    float* Eq    = ws;                  // 256K floats
    float* Ek4   = ws + 262144;         // 256K (d-quad-interleaved Ek)
    float* ctxA  = ws + 524288;         // 256K (unnormalized half-0 context)
    float* ctxB  = ws + 786432;         // 256K (unnormalized half-1 context)
    float* SpA   = ws + 1048576;        // 1K (half softmax denominators)
    float* SpB   = ws + 1049600;        // 1K
    float* sA    = ws + 1050624;        // 1K (half stage-2 partial scores)
    float* sB    = ws + 1051648;        // 1K

    gemm_exp_kernel<<<256, 256, 0, stream>>>(f_r, W_w, W_b, f_rp, Wp_w, Wp_b, Eq, Ek4, out);
    fused_attn_kernel<<<512, 1024, 0, stream>>>(Eq, Ek4, w_w, f_rp, wp_w,
                                                ctxA, ctxB, SpA, SpB, sA, sB);
    pool_kernel<<<256, 256, 0, stream>>>(ctxA, ctxB, SpA, SpB, sA, sB, out);
}

// Round 9
// 120.332 us; speedup vs baseline: 2.8591x; 1.0126x over previous
//
#include <hip/hip_runtime.h>

#define NN 1024
#define MM 1024
#define DD 256

typedef float floatx2 __attribute__((ext_vector_type(2)));

__device__ __forceinline__ float rcp_fast(float x) { return __builtin_amdgcn_rcpf(x); }

// ---- hand-emitted packed-fp32 VOP3P (LLVM won't auto-form these from ext-vector f32) ----
__device__ __forceinline__ floatx2 pk_mul(floatx2 a, floatx2 b) {
    floatx2 d;
    asm("v_pk_mul_f32 %0, %1, %2" : "=v"(d) : "v"(a), "v"(b));
    return d;
}
__device__ __forceinline__ floatx2 pk_fma(floatx2 a, floatx2 b, floatx2 c) {
    floatx2 d;
    asm("v_pk_fma_f32 %0, %1, %2, %3" : "=v"(d) : "v"(a), "v"(b), "v"(c));
    return d;
}
// uniform-operand variants: b lives in an even-aligned SGPR pair (1 SGPR read/instr — legal)
__device__ __forceinline__ floatx2 pk_mul_vs(floatx2 a, floatx2 b) {
    floatx2 d;
    asm("v_pk_mul_f32 %0, %1, %2" : "=v"(d) : "v"(a), "s"(b));
    return d;
}
__device__ __forceinline__ floatx2 pk_fma_vs(floatx2 a, floatx2 b, floatx2 c) {
    floatx2 d;
    asm("v_pk_fma_f32 %0, %1, %2, %3" : "=v"(d) : "v"(a), "s"(b), "v"(c));
    return d;
}

// ---------------- K1: fused dual GEMM + exp epilogue (unchanged from round 8) ----------------
// blocks 0..127:   q = f_r @ W_w^T + W_b    -> Eq[n][d] = exp(2q)  (clamped +-5)
// blocks 128..255: k = f_rp @ Wp_w^T + Wp_b -> Ek4 in d-quad-interleaved layout:
//   element (m, d) at Ek4[(d>>2)*4*MM + m*4 + (d&3)] — so K2's per-m float4 load
//   of 4 consecutive d is coalesced across consecutive-m lanes.
// Block 0 also zeroes d_out for K3's atomicAdd.
__global__ __launch_bounds__(256) void gemm_exp_kernel(
    const float* __restrict__ f_r,  const float* __restrict__ W_w,  const float* __restrict__ W_b,
    const float* __restrict__ f_rp, const float* __restrict__ Wp_w, const float* __restrict__ Wp_b,
    float* __restrict__ Eq, float* __restrict__ Ek4, float* __restrict__ out0)
{
    __shared__ float As[32][36];   // [k][r]
    __shared__ float Bs[32][68];   // [k][d]
    __shared__ float4 T4[32][17];  // k-path exchange: [m_local][dq_local], +1 pad

    const int b = blockIdx.x;
    const int t = threadIdx.x;
    if (b == 0) out0[t] = 0.f;     // zero d_out (256 floats)

    const int mat  = b >> 7;
    const int tile = b & 127;
    const int rt = tile & 31, dt = tile >> 5;
    const float* __restrict__ A    = mat ? f_rp : f_r;
    const float* __restrict__ B    = mat ? Wp_w : W_w;
    const float* __restrict__ bias = mat ? Wp_b : W_b;

    const int tx = t & 15, ty = t >> 4;          // tx -> 4 d-cols (one d-quad), ty -> 2 r-rows
    const int r0 = rt * 32, d0 = dt * 64;
    const int ar = t >> 3, ak = (t & 7) * 4;     // A stage: 32 rows x 32 k
    const int br = t >> 2, bk = (t & 3) * 8;     // B stage: 64 rows x 32 k

    float acc[2][4];
    #pragma unroll
    for (int i = 0; i < 2; ++i)
        #pragma unroll
        for (int j = 0; j < 4; ++j) acc[i][j] = 0.f;

    for (int kk = 0; kk < DD; kk += 32) {
        float4 av  = *(const float4*)(A + (size_t)(r0 + ar) * DD + kk + ak);
        float4 bv0 = *(const float4*)(B + (size_t)(d0 + br) * DD + kk + bk);
        float4 bv1 = *(const float4*)(B + (size_t)(d0 + br) * DD + kk + bk + 4);
        __syncthreads();
        As[ak + 0][ar] = av.x; As[ak + 1][ar] = av.y; As[ak + 2][ar] = av.z; As[ak + 3][ar] = av.w;
        Bs[bk + 0][br] = bv0.x; Bs[bk + 1][br] = bv0.y; Bs[bk + 2][br] = bv0.z; Bs[bk + 3][br] = bv0.w;
        Bs[bk + 4][br] = bv1.x; Bs[bk + 5][br] = bv1.y; Bs[bk + 6][br] = bv1.z; Bs[bk + 7][br] = bv1.w;
        __syncthreads();
        #pragma unroll
        for (int k = 0; k < 32; ++k) {
            float2 a2 = *(const float2*)&As[k][ty * 2];
            float4 b4 = *(const float4*)&Bs[k][tx * 4];
            float aa[2] = {a2.x, a2.y};
            float bb[4] = {b4.x, b4.y, b4.z, b4.w};
            #pragma unroll
            for (int i = 0; i < 2; ++i)
                #pragma unroll
                for (int j = 0; j < 4; ++j)
                    acc[i][j] = fmaf(aa[i], bb[j], acc[i][j]);
        }
    }

    float bj[4];
    #pragma unroll
    for (int j = 0; j < 4; ++j) bj[j] = bias[d0 + tx * 4 + j];

    float e[2][4];
    #pragma unroll
    for (int i = 0; i < 2; ++i)
        #pragma unroll
        for (int j = 0; j < 4; ++j) {
            float v = acc[i][j] + bj[j];
            // +-5: tanh(5)=0.9999092 (error 9e-5, negligible after w-weighting);
            // also bounds the no-max exp in K2: |s~| <= 2*sum|w| <= 32 -> e^32 << fp32 max.
            v = fminf(fmaxf(v, -5.f), 5.f);
            e[i][j] = __expf(2.f * v);
        }

    if (mat == 0) {
        #pragma unroll
        for (int i = 0; i < 2; ++i)
            *(float4*)&Eq[(size_t)(r0 + ty * 2 + i) * DD + d0 + tx * 4] =
                make_float4(e[i][0], e[i][1], e[i][2], e[i][3]);
    } else {
        // thread holds m = r0+ty*2+i, d-quad dq_local = tx, j = d&3 contiguous.
        __syncthreads();
        #pragma unroll
        for (int i = 0; i < 2; ++i)
            T4[ty * 2 + i][tx] = make_float4(e[i][0], e[i][1], e[i][2], e[i][3]);
        __syncthreads();
        const int sm = t & 31, sq = t >> 5;   // sm -> m_local, sq -> dq_local (2 halves)
        #pragma unroll
        for (int h = 0; h < 2; ++h) {
            const int dql = sq + 8 * h;
            float4 v = T4[sm][dql];
            // coalesced: consecutive sm lanes -> consecutive m -> +16B stride
            *(float4*)&Ek4[(size_t)((d0 >> 2) + dql) * (4 * MM) + (size_t)(r0 + sm) * 4] = v;
        }
    }
}

// ---------------- K2: n=8 m-split mega kernel, pk phase A ----------------
// ROUND 9: n-blocking 4->8. 256 blocks x 1024 thr; block = (n-oct = bid>>1,
// m-half = bid&1). Each EkT/frp byte now feeds 8 output rows -> phase-A EkT
// traffic 268->134 MB AND phase-C frp traffic 268->134 MB (single-pass C,
// each frp element read once per block). VALU total unchanged (pk inner loop,
// 8 accumulators). LDS 144 KB -> 1 block/CU, 16 waves (rounds 1/7: 16-vs-32
// waves is perf-neutral here). Residual risk: phase-transition drain at 1 blk/CU.
// Phase A: lane owns ONE m (t&511), tg = t>>9 -> d-half; 14 pk + 2 rcp per (n,8d).
// Phase B: 2-slab combine + NO-MAX exp (|s~|<=32); partial denom -> Sp.
// Phase C: ctx~_half = e @ frp[m-half]; 16 ranges x 64 d-quads, all 8 n/thread.
__global__ __launch_bounds__(1024, 4) void fused_attn_kernel(
    const float* __restrict__ Eq, const float* __restrict__ Ek4,
    const float* __restrict__ w_w, const float* __restrict__ frp,
    const float* __restrict__ wp_w,
    float* __restrict__ ctxA, float* __restrict__ ctxB,
    float* __restrict__ SpA, float* __restrict__ SpB,
    float* __restrict__ sA,  float* __restrict__ sB)
{
    // union region: part (phase A->B, 32KB) aliases ctxred (phase C, 128KB);
    // lifetimes separated by the phase-B barrier.
    __shared__ __align__(16) char usm_raw[131072];
    float (*part)[8][512]   = (float (*)[8][512])(void*)usm_raw;   // [2][8][512] 32KB
    float4 (*ctxred)[8][64] = (float4 (*)[8][64])(void*)usm_raw;   // [16][8][64] 128KB
    __shared__ float alsm[8][512];   // 16KB unnormalized e
    __shared__ float redsm[8][2];
    __shared__ float redsc[8][2];

    const int t  = threadIdx.x;
    const int bm = blockIdx.x & 1;
    const int n0 = (blockIdx.x >> 1) * 8;
    const int m0 = bm * 512;

    // ---- Phase A: lane = 1 m, tg = d-half of 128; 16 chunks of 8 d ----
    const int m_l = t & 511;
    const int tg  = t >> 9;                                   // wave-uniform
    const int dbase = __builtin_amdgcn_readfirstlane(tg * 128);
    const float* __restrict__ eqb = Eq + (size_t)n0 * DD + dbase;
    const float* __restrict__ wwb = w_w + dbase;
    const float* __restrict__ ekb = Ek4 + (size_t)(dbase >> 2) * (4 * MM) + (size_t)(m0 + m_l) * 4;

    const floatx2 one2 = {1.f, 1.f};
    floatx2 acc[8];
    #pragma unroll
    for (int n = 0; n < 8; ++n) acc[n] = (floatx2){0.f, 0.f};

    for (int c8 = 0; c8 < 16; ++c8) {
        float4 ekA = *(const float4*)(ekb + (size_t)(2 * c8 + 0) * (4 * MM));
        float4 ekB = *(const float4*)(ekb + (size_t)(2 * c8 + 1) * (4 * MM));
        floatx2 ek01 = {ekA.x, ekA.y}, ek23 = {ekA.z, ekA.w};
        floatx2 ek45 = {ekB.x, ekB.y}, ek67 = {ekB.z, ekB.w};
        const int db = c8 * 8;
        floatx2 w01 = *(const floatx2*)(wwb + db + 0);   // uniform -> SGPR pairs
        floatx2 w23 = *(const floatx2*)(wwb + db + 2);
        floatx2 w45 = *(const floatx2*)(wwb + db + 4);
        floatx2 w67 = *(const floatx2*)(wwb + db + 6);
        #pragma unroll
        for (int n = 0; n < 8; ++n) {
            const float* qn = eqb + (size_t)n * DD + db;   // uniform -> s_load
            floatx2 q01 = *(const floatx2*)(qn + 0);
            floatx2 q23 = *(const floatx2*)(qn + 2);
            floatx2 q45 = *(const floatx2*)(qn + 4);
            floatx2 q67 = *(const floatx2*)(qn + 6);
            // x_d = Eq*Ek + 1 (per-half independent d's)
            floatx2 x01 = pk_fma_vs(ek01, q01, one2);
            floatx2 x23 = pk_fma_vs(ek23, q23, one2);
            floatx2 x45 = pk_fma_vs(ek45, q45, one2);
            floatx2 x67 = pk_fma_vs(ek67, q67, one2);
            // level 1: w/x pairwise combine
            floatx2 den1 = pk_mul(x01, x23);
            floatx2 num1 = pk_fma_vs(x01, w23, pk_mul_vs(x23, w01));
            floatx2 den2 = pk_mul(x45, x67);
            floatx2 num2 = pk_fma_vs(x45, w67, pk_mul_vs(x67, w45));
            // level 2: 4-way products (<= e^80, fp32-safe)
            floatx2 DEN = pk_mul(den1, den2);
            floatx2 NUM = pk_fma(num2, den1, pk_mul(num1, den2));
            floatx2 r2; r2.x = rcp_fast(DEN.x); r2.y = rcp_fast(DEN.y);
            acc[n] = pk_fma(NUM, r2, acc[n]);
        }
    }

    #pragma unroll
    for (int n = 0; n < 8; ++n)
        part[tg][n][m_l] = acc[n].x + acc[n].y;   // conflict-free: stride-1 lanes
    __syncthreads();

    // ---- Phase B: combine d-halves + no-max exp; thread -> (n = t>>7, 4 m = t&127) ----
    {
        const int bn = t >> 7, bj = t & 127;
        float4 a0 = *(const float4*)&part[0][bn][4 * bj];
        float4 a1 = *(const float4*)&part[1][bn][4 * bj];
        float e0 = __expf(-2.f * (a0.x + a1.x));   // bounded: |s~| <= 32
        float e1 = __expf(-2.f * (a0.y + a1.y));
        float e2 = __expf(-2.f * (a0.z + a1.z));
        float e3 = __expf(-2.f * (a0.w + a1.w));
        *(float4*)&alsm[bn][4 * bj] = make_float4(e0, e1, e2, e3);
        float sm = (e0 + e1) + (e2 + e3);
        #pragma unroll
        for (int off = 32; off > 0; off >>= 1) sm += __shfl_xor(sm, off);
        if ((t & 63) == 0) redsm[bn][(t >> 6) & 1] = sm;   // bn wave-uniform (t>>7)
    }
    __syncthreads();   // alsm+redsm ready; part dead -> ctxred alias safe
    if (t < 8) {
        float* Sp = bm ? SpB : SpA;
        Sp[n0 + t] = redsm[t][0] + redsm[t][1];
    }

    // ---- Phase C: ctx~ = e @ frp; thread = (m-range rr = t>>6, d-quad cc = t&63), 8 n ----
    const int rr = t >> 6;        // 16 ranges of 32 m (wave-uniform)
    const int cc = t & 63;        // d-cols 4cc..4cc+3
    floatx2 axl[8], axh[8];
    #pragma unroll
    for (int n = 0; n < 8; ++n) { axl[n] = (floatx2){0.f,0.f}; axh[n] = (floatx2){0.f,0.f}; }
    const float* fb = frp + (size_t)(m0 + rr * 32) * DD + 4 * cc;
    for (int mq = 0; mq < 8; ++mq) {
        float alv[8][4];
        #pragma unroll
        for (int n = 0; n < 8; ++n) {
            float4 a4 = *(const float4*)&alsm[n][rr * 32 + mq * 4];   // uniform -> broadcast
            alv[n][0] = a4.x; alv[n][1] = a4.y; alv[n][2] = a4.z; alv[n][3] = a4.w;
        }
        #pragma unroll
        for (int mm = 0; mm < 4; ++mm) {
            float4 f = *(const float4*)(fb + (size_t)(mq * 4 + mm) * DD);
            floatx2 fl = {f.x, f.y}, fh = {f.z, f.w};
            #pragma unroll
            for (int n = 0; n < 8; ++n) {
                axl[n] += alv[n][mm] * fl;
                axh[n] += alv[n][mm] * fh;
            }
        }
    }
    #pragma unroll
    for (int n = 0; n < 8; ++n)
        ctxred[rr][n][cc] = make_float4(axl[n].x, axl[n].y, axh[n].x, axh[n].y);
    __syncthreads();

    // final range-reduce: thread t -> (n = t>>7, d = t&127 and d+128)
    const int fn = t >> 7, fd = t & 127;
    float s_lo = 0.f, s_hi = 0.f;
    #pragma unroll
    for (int r = 0; r < 16; ++r) {
        s_lo += ((const float*)&ctxred[r][fn][fd >> 2])[fd & 3];
        s_hi += ((const float*)&ctxred[r][fn][(fd >> 2) + 32])[fd & 3];
    }
    float* ctxP = bm ? ctxB : ctxA;
    ctxP[(size_t)(n0 + fn) * DD + fd]       = s_lo;
    ctxP[(size_t)(n0 + fn) * DD + fd + 128] = s_hi;

    // stage-2 partial score: s~_half[n] = ctx~_half[n] . wp_w
    float p = s_lo * wp_w[fd] + s_hi * wp_w[fd + 128];
    #pragma unroll
    for (int off = 32; off > 0; off >>= 1) p += __shfl_xor(p, off);
    if ((t & 63) == 0) redsc[fn][(t >> 6) & 1] = p;        // fn wave-uniform
    __syncthreads();
    if (t < 8) {
        float* sP = bm ? sB : sA;
        sP[n0 + t] = redsc[t][0] + redsc[t][1];
    }
}

// ---------------- K3: softmax over N (redundant per block) + pooled sum ----------------
// 256 blocks x 256 thr; block b handles n-rows 4b..4b+3.
// score[row] = (sA+sB)/(SpA+SpB) reconstructed from 4 scalars.
__global__ __launch_bounds__(256) void pool_kernel(
    const float* __restrict__ ctxA, const float* __restrict__ ctxB,
    const float* __restrict__ SpA,  const float* __restrict__ SpB,
    const float* __restrict__ sA,   const float* __restrict__ sB,
    float* __restrict__ out)
{
    __shared__ float red[8];
    const int t = threadIdx.x, lane = t & 63, wid = t >> 6;
    const int n0 = blockIdx.x * 4;

    float sc[4];
    #pragma unroll
    for (int i = 0; i < 4; ++i) {
        int r = t + 256 * i;
        sc[i] = (sA[r] + sB[r]) * rcp_fast(SpA[r] + SpB[r]);
    }
    float mx = fmaxf(fmaxf(sc[0], sc[1]), fmaxf(sc[2], sc[3]));
    #pragma unroll
    for (int off = 32; off > 0; off >>= 1) mx = fmaxf(mx, __shfl_xor(mx, off));
    if (lane == 0) red[wid] = mx;
    __syncthreads();
    mx = fmaxf(fmaxf(red[0], red[1]), fmaxf(red[2], red[3]));

    float se = __expf(sc[0] - mx) + __expf(sc[1] - mx) + __expf(sc[2] - mx) + __expf(sc[3] - mx);
    #pragma unroll
    for (int off = 32; off > 0; off >>= 1) se += __shfl_xor(se, off);
    if (lane == 0) red[4 + wid] = se;
    __syncthreads();
    se = red[4] + red[5] + red[6] + red[7];
    float invS = rcp_fast(se);

    float racc = 0.f;
    #pragma unroll
    for (int i = 0; i < 4; ++i) {
        int row = n0 + i;
        float invRow = rcp_fast(SpA[row] + SpB[row]);      // wave-uniform scalar loads
        float scr = (sA[row] + sB[row]) * invRow;
        float ap = __expf(scr - mx) * invS;
        float cr = (ctxA[(size_t)row * DD + t] + ctxB[(size_t)row * DD + t]) * invRow;
        racc = fmaf(ap, cr, racc);
    }
    atomicAdd(out + t, racc);
}

extern "C" void kernel_launch(void* const* d_in, const int* in_sizes, int n_in,
                              void* d_out, int out_size, void* d_ws, size_t ws_size,
                              hipStream_t stream) {
    const float* f_r  = (const float*)d_in[0];
    const float* f_rp = (const float*)d_in[1];
    const float* W_w  = (const float*)d_in[2];
    const float* W_b  = (const float*)d_in[3];
    const float* Wp_w = (const float*)d_in[4];
    const float* Wp_b = (const float*)d_in[5];
    const float* w_w  = (const float*)d_in[6];
    // d_in[7] = w_b  : cancels in softmax over m
    const float* wp_w = (const float*)d_in[8];
    // d_in[9] = wp_b : cancels in softmax over n
    float* out = (float*)d_out;

    float* ws    = (float*)d_ws;
    float* Eq    = ws;                  // 256K floats
    float* Ek4   = ws + 262144;         // 256K (d-quad-interleaved Ek)
    float* ctxA  = ws + 524288;         // 256K (unnormalized half-0 context)
    float* ctxB  = ws + 786432;         // 256K (unnormalized half-1 context)
    float* SpA   = ws + 1048576;        // 1K (half softmax denominators)
    float* SpB   = ws + 1049600;        // 1K
    float* sA    = ws + 1050624;        // 1K (half stage-2 partial scores)
    float* sB    = ws + 1051648;        // 1K

    gemm_exp_kernel<<<256, 256, 0, stream>>>(f_r, W_w, W_b, f_rp, Wp_w, Wp_b, Eq, Ek4, out);
    fused_attn_kernel<<<256, 1024, 0, stream>>>(Eq, Ek4, w_w, f_rp, wp_w,
                                                ctxA, ctxB, SpA, SpB, sA, sB);
    pool_kernel<<<256, 256, 0, stream>>>(ctxA, ctxB, SpA, SpB, sA, sB, out);
}